// Round 1
// baseline (522.157 us; speedup 1.0000x reference)
//
#include <hip/hip_runtime.h>

// y = irfft(rfft(x, axis=1, ortho) * H, n=T, axis=1, ortho)
// x: [B=8, T=8192, F=512] f32, H: [F, FREQ=4097, 2] f32, y: [B, T, F] f32
//
// Per (b, f): length-8192 real FFT -> filter -> inverse. Combined ortho norms
// give plain DFT then IDFT(1/N). irfft ignores Im of bins 0 and N/2 (pocketfft
// c2r semantics), so only Re(H) acts there.
//
// Implementation: pack two adjacent feature columns as one complex signal
// (z = x[:,2j] + i x[:,2j+1], contiguous float2 in memory). Forward radix-2
// DIF (natural->bitrev), untangle + filter + repack in the bit-reversed
// domain (pairs (k,N-k) touch disjoint LDS slots -> no barrier), inverse
// radix-2 DIT (bitrev->natural), scale 1/N, store float2.

#define THREADS 512
#define LOGN 13
#define NFFT 8192
#define TT 8192
#define FF 512
#define FREQ 4097

__global__ __launch_bounds__(THREADS) void fft_filter_kernel(
    const float* __restrict__ x, const float* __restrict__ H,
    float* __restrict__ y)
{
    __shared__ float re[NFFT];
    __shared__ float im[NFFT];

    const int tid = threadIdx.x;

    // XCD-chunked swizzle: 2048 blocks, 8 XCDs round-robin on raw blockIdx.
    // XCD x gets ids [x*256, x*256+256) == batch b=x, all f-pairs; the 8
    // f-pair neighbors sharing each 64B line run concurrently on one XCD.
    const int wg = blockIdx.x;
    const int id = (wg & 7) * 256 + (wg >> 3);
    const int b  = id >> 8;    // batch
    const int j  = id & 255;   // f-pair index, f0 = 2j, f1 = 2j+1

    const float2* __restrict__ xp = (const float2*)x;
    float2* __restrict__ yp = (float2*)y;
    const size_t base = (size_t)b * TT * (FF / 2) + j;  // float2 idx of (b,0,f0)

    // ---- load: z_t = x[b,t,f0] + i x[b,t,f1] ----
#pragma unroll
    for (int q = 0; q < NFFT / THREADS; ++q) {
        const int t = tid + q * THREADS;
        const float2 v = xp[base + (size_t)t * (FF / 2)];
        re[t] = v.x;
        im[t] = v.y;
    }
    __syncthreads();

    // ---- forward: radix-2 DIF, natural in -> bit-reversed out ----
    for (int s = 0; s < LOGN; ++s) {
        const int shift = LOGN - 1 - s;      // half = 1 << shift
        const int half = NFFT >> (s + 1);
        const float invL = ldexpf(1.0f, s - LOGN);  // 1/L, L = N>>s
#pragma unroll
        for (int q = 0; q < NFFT / 2 / THREADS; ++q) {
            const int jj = tid + q * THREADS;
            const int p = jj & (half - 1);
            const int i0 = ((jj >> shift) << (shift + 1)) + p;
            const int i1 = i0 + half;
            const float ar = re[i0], ai = im[i0];
            const float br = re[i1], bi = im[i1];
            const float ang = -6.283185307179586f * (float)p * invL;
            float sn, cs;
            __sincosf(ang, &sn, &cs);
            re[i0] = ar + br;
            im[i0] = ai + bi;
            const float dr = ar - br, di = ai - bi;
            re[i1] = dr * cs - di * sn;
            im[i1] = dr * sn + di * cs;
        }
        __syncthreads();
    }

    // ---- untangle two real spectra, apply filters, repack (bitrev domain) ----
    const float2* __restrict__ Hp = (const float2*)H;  // [F][FREQ] complex
    const size_t hb0 = (size_t)(2 * j) * FREQ;
    const size_t hb1 = hb0 + FREQ;
#pragma unroll
    for (int q = 0; q < NFFT / 2 / THREADS; ++q) {
        const int k = tid + q * THREADS;  // 0..4095
        if (k == 0) {
            // bin 0 at pos rev(0)=0: Xa=Re(Z0), Xb=Im(Z0), real; keep Re only
            const float zr = re[0], zi = im[0];
            const float2 ha = Hp[hb0 + 0];
            const float2 hbv = Hp[hb1 + 0];
            re[0] = zr * ha.x;
            im[0] = zi * hbv.x;
            // Nyquist k=4096 at pos rev(4096)=1
            const float zr2 = re[1], zi2 = im[1];
            const float2 ha2 = Hp[hb0 + 4096];
            const float2 hb2 = Hp[hb1 + 4096];
            re[1] = zr2 * ha2.x;
            im[1] = zi2 * hb2.x;
        } else {
            const int pk = __brev((unsigned)k) >> (32 - LOGN);
            const int pn = __brev((unsigned)(NFFT - k)) >> (32 - LOGN);
            const float z1r = re[pk], z1i = im[pk];
            const float z2r = re[pn], z2i = im[pn];
            // spectra of the two real signals
            const float xar = 0.5f * (z1r + z2r), xai = 0.5f * (z1i - z2i);
            const float xbr = 0.5f * (z1i + z2i), xbi = 0.5f * (z2r - z1r);
            const float2 ha = Hp[hb0 + k];
            const float2 hbv = Hp[hb1 + k];
            const float yar = xar * ha.x - xai * ha.y;
            const float yai = xar * ha.y + xai * ha.x;
            const float ybr = xbr * hbv.x - xbi * hbv.y;
            const float ybi = xbr * hbv.y + xbi * hbv.x;
            // W_k = Ya + i*Yb ; W_{N-k} = conj(Ya) + i*conj(Yb)
            re[pk] = yar - ybi;
            im[pk] = yai + ybr;
            re[pn] = yar + ybi;
            im[pn] = ybr - yai;
        }
    }
    __syncthreads();

    // ---- inverse: radix-2 DIT (adjoint of fwd), bitrev in -> natural out ----
    for (int s = LOGN - 1; s >= 0; --s) {
        const int shift = LOGN - 1 - s;
        const int half = NFFT >> (s + 1);
        const float invL = ldexpf(1.0f, s - LOGN);
#pragma unroll
        for (int q = 0; q < NFFT / 2 / THREADS; ++q) {
            const int jj = tid + q * THREADS;
            const int p = jj & (half - 1);
            const int i0 = ((jj >> shift) << (shift + 1)) + p;
            const int i1 = i0 + half;
            const float ar = re[i0], ai = im[i0];
            const float br = re[i1], bi = im[i1];
            const float ang = 6.283185307179586f * (float)p * invL;
            float sn, cs;
            __sincosf(ang, &sn, &cs);
            const float tr = br * cs - bi * sn;
            const float ti = br * sn + bi * cs;
            re[i0] = ar + tr;
            im[i0] = ai + ti;
            re[i1] = ar - tr;
            im[i1] = ai - ti;
        }
        __syncthreads();
    }

    // ---- store: y[b,t,f0] = Re/N, y[b,t,f1] = Im/N ----
    const float scale = 1.0f / (float)NFFT;
#pragma unroll
    for (int q = 0; q < NFFT / THREADS; ++q) {
        const int t = tid + q * THREADS;
        float2 v;
        v.x = re[t] * scale;
        v.y = im[t] * scale;
        yp[base + (size_t)t * (FF / 2)] = v;
    }
}

extern "C" void kernel_launch(void* const* d_in, const int* in_sizes, int n_in,
                              void* d_out, int out_size, void* d_ws, size_t ws_size,
                              hipStream_t stream) {
    const float* x = (const float*)d_in[0];
    const float* H = (const float*)d_in[1];
    float* y = (float*)d_out;
    // 8 batches * 256 f-pairs = 2048 workgroups
    fft_filter_kernel<<<dim3(2048), dim3(THREADS), 0, stream>>>(x, H, y);
}

// Round 2
// 509.777 us; speedup vs baseline: 1.0243x; 1.0243x over previous
//
#include <hip/hip_runtime.h>

// y = irfft(rfft(x, axis=1, ortho) * H, n=T, axis=1, ortho)
// x: [B=8, T=8192, F=512] f32, H: [F, FREQ=4097, 2] f32, y: [B, T, F] f32
//
// Pack two adjacent feature columns as one complex signal. Forward radix-2
// DIF (natural->bitrev), untangle + filter + repack in the bit-reversed
// domain, inverse radix-2 DIT (bitrev->natural).
//
// Round 2 changes (theory: kill LDS bank conflicts, 37% of cycles):
//  - untangle enumerated by LDS *position* u (lane-consecutive), active when
//    u < partner(u); partner positions provably spread over all banks.
//  - LDS padded 1 word per 32 (IDX) to kill 4/8-way mid-stage conflicts.
//  - 1/N folded into filter coefficients; store is a plain copy.

#define THREADS 512
#define LOGN 13
#define NFFT 8192
#define TT 8192
#define FF 512
#define FREQ 4097

#define IDX(i) ((i) + ((i) >> 5))
#define LDS_SZ (NFFT + NFFT / 32)

__global__ __launch_bounds__(THREADS) void fft_filter_kernel(
    const float* __restrict__ x, const float* __restrict__ H,
    float* __restrict__ y)
{
    __shared__ float re[LDS_SZ];
    __shared__ float im[LDS_SZ];

    const int tid = threadIdx.x;

    // XCD-chunked swizzle: 8 XCDs round-robin on raw blockIdx; neighbors in f
    // (sharing cache lines) land on the same XCD.
    const int wg = blockIdx.x;
    const int id = (wg & 7) * 256 + (wg >> 3);
    const int b  = id >> 8;    // batch
    const int j  = id & 255;   // f-pair index, f0 = 2j, f1 = 2j+1

    const float2* __restrict__ xp = (const float2*)x;
    float2* __restrict__ yp = (float2*)y;
    const size_t base = (size_t)b * TT * (FF / 2) + j;  // float2 idx of (b,0,f0)

    // ---- load: z_t = x[b,t,f0] + i x[b,t,f1] ----
#pragma unroll
    for (int q = 0; q < NFFT / THREADS; ++q) {
        const int t = tid + q * THREADS;
        const float2 v = xp[base + (size_t)t * (FF / 2)];
        re[IDX(t)] = v.x;
        im[IDX(t)] = v.y;
    }
    __syncthreads();

    // ---- forward: radix-2 DIF, natural in -> bit-reversed out ----
    for (int s = 0; s < LOGN; ++s) {
        const int shift = LOGN - 1 - s;      // half = 1 << shift
        const int half = NFFT >> (s + 1);
        const float invL = ldexpf(1.0f, s - LOGN);  // 1/L, L = N>>s
#pragma unroll
        for (int q = 0; q < NFFT / 2 / THREADS; ++q) {
            const int jj = tid + q * THREADS;
            const int p = jj & (half - 1);
            const int i0 = ((jj >> shift) << (shift + 1)) + p;
            const int i1 = i0 + half;
            const int a0 = IDX(i0), a1 = IDX(i1);
            const float ar = re[a0], ai = im[a0];
            const float br = re[a1], bi = im[a1];
            const float ang = -6.283185307179586f * (float)p * invL;
            float sn, cs;
            __sincosf(ang, &sn, &cs);
            re[a0] = ar + br;
            im[a0] = ai + bi;
            const float dr = ar - br, di = ai - bi;
            re[a1] = dr * cs - di * sn;
            im[a1] = dr * sn + di * cs;
        }
        __syncthreads();
    }

    // ---- untangle + filter + repack, enumerated by LDS position ----
    // Position u holds bin k = rev13(u). Pair partner (bin N-k) sits at
    // pn = rev13(N - k). Each unordered pair processed once (u < pn);
    // lane-consecutive u makes both own and partner accesses conflict-free.
    const float2* __restrict__ Hp = (const float2*)H;  // [F][FREQ] complex
    const size_t hb0 = (size_t)(2 * j) * FREQ;
    const size_t hb1 = hb0 + FREQ;
    const float invN = 1.0f / (float)NFFT;
#pragma unroll
    for (int q = 0; q < NFFT / THREADS; ++q) {
        const int u = tid + q * THREADS;
        if (u == 0) {
            // bin 0 at position 0: Xa=Re(Z0), Xb=Im(Z0), real; Re(H) only
            const float zr = re[IDX(0)], zi = im[IDX(0)];
            const float2 ha = Hp[hb0 + 0];
            const float2 hbv = Hp[hb1 + 0];
            re[IDX(0)] = zr * ha.x * invN;
            im[IDX(0)] = zi * hbv.x * invN;
        } else if (u == 1) {
            // Nyquist bin 4096 at position rev(4096)=1
            const float zr = re[IDX(1)], zi = im[IDX(1)];
            const float2 ha = Hp[hb0 + 4096];
            const float2 hbv = Hp[hb1 + 4096];
            re[IDX(1)] = zr * ha.x * invN;
            im[IDX(1)] = zi * hbv.x * invN;
        } else {
            const int k = __brev((unsigned)u) >> (32 - LOGN);   // bin at u
            const int pn = __brev((unsigned)(NFFT - k)) >> (32 - LOGN);
            if (u < pn) {
                // klo = bin index < 4096 of this pair; pz = its position
                const bool swapd = (k > NFFT / 2);
                const int klo = swapd ? (NFFT - k) : k;
                const int pz = swapd ? pn : u;
                const int pw = swapd ? u : pn;
                const int az = IDX(pz), aw = IDX(pw);
                const float z1r = re[az], z1i = im[az];   // Z_klo
                const float z2r = re[aw], z2i = im[aw];   // Z_{N-klo}
                const float xar = 0.5f * (z1r + z2r), xai = 0.5f * (z1i - z2i);
                const float xbr = 0.5f * (z1i + z2i), xbi = 0.5f * (z2r - z1r);
                const float2 ha = Hp[hb0 + klo];
                const float2 hbv = Hp[hb1 + klo];
                const float har = ha.x * invN, hai = ha.y * invN;
                const float hbr = hbv.x * invN, hbi = hbv.y * invN;
                const float yar = xar * har - xai * hai;
                const float yai = xar * hai + xai * har;
                const float ybr = xbr * hbr - xbi * hbi;
                const float ybi = xbr * hbi + xbi * hbr;
                // W at pz = Ya + i*Yb ; at pw = conj(Ya) + i*conj(Yb)
                re[az] = yar - ybi;
                im[az] = yai + ybr;
                re[aw] = yar + ybi;
                im[aw] = ybr - yai;
            }
        }
    }
    __syncthreads();

    // ---- inverse: radix-2 DIT (adjoint of fwd), bitrev in -> natural out ----
    for (int s = LOGN - 1; s >= 0; --s) {
        const int shift = LOGN - 1 - s;
        const int half = NFFT >> (s + 1);
        const float invL = ldexpf(1.0f, s - LOGN);
#pragma unroll
        for (int q = 0; q < NFFT / 2 / THREADS; ++q) {
            const int jj = tid + q * THREADS;
            const int p = jj & (half - 1);
            const int i0 = ((jj >> shift) << (shift + 1)) + p;
            const int i1 = i0 + half;
            const int a0 = IDX(i0), a1 = IDX(i1);
            const float ar = re[a0], ai = im[a0];
            const float br = re[a1], bi = im[a1];
            const float ang = 6.283185307179586f * (float)p * invL;
            float sn, cs;
            __sincosf(ang, &sn, &cs);
            const float tr = br * cs - bi * sn;
            const float ti = br * sn + bi * cs;
            re[a0] = ar + tr;
            im[a0] = ai + ti;
            re[a1] = ar - tr;
            im[a1] = ai - ti;
        }
        __syncthreads();
    }

    // ---- store: y[b,t,f0] = Re, y[b,t,f1] = Im (1/N already folded) ----
#pragma unroll
    for (int q = 0; q < NFFT / THREADS; ++q) {
        const int t = tid + q * THREADS;
        float2 v;
        v.x = re[IDX(t)];
        v.y = im[IDX(t)];
        yp[base + (size_t)t * (FF / 2)] = v;
    }
}

extern "C" void kernel_launch(void* const* d_in, const int* in_sizes, int n_in,
                              void* d_out, int out_size, void* d_ws, size_t ws_size,
                              hipStream_t stream) {
    const float* x = (const float*)d_in[0];
    const float* H = (const float*)d_in[1];
    float* y = (float*)d_out;
    // 8 batches * 256 f-pairs = 2048 workgroups
    fft_filter_kernel<<<dim3(2048), dim3(THREADS), 0, stream>>>(x, H, y);
}

// Round 3
// 419.315 us; speedup vs baseline: 1.2453x; 1.2157x over previous
//
#include <hip/hip_runtime.h>

// y = irfft(rfft(x, axis=1, ortho) * H, n=T, axis=1, ortho)
// x: [B=8, T=8192, F=512] f32, H: [F, FREQ=4097, 2] f32, y: [B, T, F] f32
//
// Round 3: mixed-radix register FFT. 8192 = 16*16*(16*2). Three phases of
// in-register 16-point DFTs (constant twiddles) + one cross-lane radix-2 via
// shfl_xor. Inter-phase twiddles: 1 sincos + 15 iterative complex mults.
// Digit-permuted frequency order (p = u1*512+u2*32+u3*2+u4 <-> k =
// u1+16*u2+256*u3+4096*u4); untangle/filter works in that order. 6 barriers
// total (was 27), ~4x fewer LDS passes, ~35x fewer sincos.

#define THREADS 512
#define NFFT 8192
#define TT 8192
#define FFD2 256   // F/2 in float2 units
#define FREQ 4097

#define IDX(i) ((i) + ((i) >> 5))
#define LDS_SZ (NFFT + NFFT / 32)

__device__ __forceinline__ float2 cmul(float2 a, float2 b) {
    return make_float2(a.x * b.x - a.y * b.y, a.x * b.y + a.y * b.x);
}

// butterfly helpers for in-place DIF: (a,b) -> (a+b, (a-b)*w)
#define BF1(i0, i1) { float2 a = v[i0], b = v[i1]; \
    v[i0] = make_float2(a.x + b.x, a.y + b.y); \
    v[i1] = make_float2(a.x - b.x, a.y - b.y); }
#define BFI(i0, i1) { float2 a = v[i0], b = v[i1]; \
    v[i0] = make_float2(a.x + b.x, a.y + b.y); \
    float dr = a.x - b.x, di = a.y - b.y; \
    v[i1] = make_float2(-di * S, dr * S); }
#define BFW(i0, i1, wr, wi) { float2 a = v[i0], b = v[i1]; \
    v[i0] = make_float2(a.x + b.x, a.y + b.y); \
    float dr = a.x - b.x, di = a.y - b.y; \
    v[i1] = make_float2(dr * (wr) - di * (wi), dr * (wi) + di * (wr)); }

// in-place 16-pt DFT, DIF, sign SGN (-1 fwd / +1 inv), input natural order,
// output at bit-reversed positions: v[p] = X[rev4(p)].
template<int SGN>
__device__ __forceinline__ void dft16(float2 v[16]) {
    constexpr float S  = (float)SGN;
    constexpr float RT = 0.70710678118654752440f;  // sqrt(2)/2
    constexpr float C1 = 0.92387953251128675613f;  // cos(pi/8)
    constexpr float S1 = 0.38268343236508977173f;  // sin(pi/8)
    // len=16: w16^p = (cos(pi p/8), S sin(pi p/8))
    BF1(0, 8); BFW(1, 9, C1, S * S1); BFW(2, 10, RT, S * RT); BFW(3, 11, S1, S * C1);
    BFI(4, 12); BFW(5, 13, -S1, S * C1); BFW(6, 14, -RT, S * RT); BFW(7, 15, -C1, S * S1);
    // len=8
    BF1(0, 4); BFW(1, 5, RT, S * RT); BFI(2, 6); BFW(3, 7, -RT, S * RT);
    BF1(8, 12); BFW(9, 13, RT, S * RT); BFI(10, 14); BFW(11, 15, -RT, S * RT);
    // len=4
    BF1(0, 2); BFI(1, 3); BF1(4, 6); BFI(5, 7);
    BF1(8, 10); BFI(9, 11); BF1(12, 14); BFI(13, 15);
    // len=2
    BF1(0, 1); BF1(2, 3); BF1(4, 5); BF1(6, 7);
    BF1(8, 9); BF1(10, 11); BF1(12, 13); BF1(14, 15);
}

__global__ __launch_bounds__(THREADS, 4) void fft_filter_kernel(
    const float* __restrict__ x, const float* __restrict__ H,
    float* __restrict__ y)
{
    __shared__ float re[LDS_SZ];
    __shared__ float im[LDS_SZ];

    const int tid = threadIdx.x;
    // XCD-chunked swizzle: f-pair neighbors (sharing cache lines) on one XCD.
    const int wg = blockIdx.x;
    const int id = (wg & 7) * 256 + (wg >> 3);
    const int b  = id >> 8;
    const int j  = id & 255;

    const float2* __restrict__ xp = (const float2*)x;
    float2* __restrict__ yp = (float2*)y;
    const size_t base = (size_t)b * TT * FFD2 + j;

    constexpr int R4[16] = {0, 8, 4, 12, 2, 10, 6, 14, 1, 9, 5, 13, 3, 11, 7, 15};
    const float TWO_PI = 6.28318530717958647692f;

    float2 v[16];

    // ---- forward P1: 8192 = 16 x 512; thread = r1, column stride 512 ----
    {
        const int r1 = tid;
#pragma unroll
        for (int t = 0; t < 16; ++t)
            v[t] = xp[base + (size_t)((t * 512 + r1) * FFD2)];
        dft16<-1>(v);
        float sn, cs;
        __sincosf(-TWO_PI * (float)r1 / 8192.0f, &sn, &cs);
        const float2 wb = make_float2(cs, sn);
        float2 w = make_float2(1.0f, 0.0f);
#pragma unroll
        for (int u = 0; u < 16; ++u) {
            const float2 val = (u == 0) ? v[0] : cmul(v[R4[u]], w);
            const int a = IDX(u * 512 + r1);
            re[a] = val.x; im[a] = val.y;
            w = cmul(w, wb);
        }
    }
    __syncthreads();

    // ---- forward P2: 16 blocks of 512 = 16 x 32 ----
    {
        const int ub = tid >> 5, r2 = tid & 31;
        const int bb = ub * 512 + r2;
#pragma unroll
        for (int t = 0; t < 16; ++t) {
            const int a = IDX(bb + t * 32);
            v[t] = make_float2(re[a], im[a]);
        }
        dft16<-1>(v);
        float sn, cs;
        __sincosf(-TWO_PI * (float)r2 / 512.0f, &sn, &cs);
        const float2 wb = make_float2(cs, sn);
        float2 w = make_float2(1.0f, 0.0f);
#pragma unroll
        for (int u = 0; u < 16; ++u) {
            const float2 val = (u == 0) ? v[0] : cmul(v[R4[u]], w);
            const int a = IDX(bb + u * 32);
            re[a] = val.x; im[a] = val.y;
            w = cmul(w, wb);
        }
    }
    __syncthreads();

    // ---- forward P3: 256 blocks of 32 = 16 x 2; radix-2 over r3 via shfl ----
    {
        const int b3 = tid >> 1, r3 = tid & 1;
        const int bb = b3 * 32 + r3;
#pragma unroll
        for (int t = 0; t < 16; ++t) {
            const int a = IDX(bb + t * 2);
            v[t] = make_float2(re[a], im[a]);
        }
        dft16<-1>(v);
        float sn, cs;
        __sincosf(-TWO_PI * (float)r3 / 32.0f, &sn, &cs);
        const float2 wb = make_float2(cs, sn);
        float2 w = make_float2(1.0f, 0.0f);
#pragma unroll
        for (int u = 0; u < 16; ++u) {
            const float2 A = (u == 0) ? v[0] : cmul(v[R4[u]], w);
            float2 o;
            o.x = __shfl_xor(A.x, 1);
            o.y = __shfl_xor(A.y, 1);
            const float2 val = r3 ? make_float2(o.x - A.x, o.y - A.y)
                                  : make_float2(A.x + o.x, A.y + o.y);
            const int a = IDX(bb + u * 2);
            re[a] = val.x; im[a] = val.y;
            w = cmul(w, wb);
        }
    }
    __syncthreads();

    // ---- untangle two real spectra + filter + repack (digit-permuted) ----
    // position p <-> bin k: k = u1 + 16*u2 + 256*u3 + 4096*u4,
    // p = u1*512 + u2*32 + u3*2 + u4.
    {
        const float2* __restrict__ Hp = (const float2*)H;
        const size_t hb0 = (size_t)(2 * j) * FREQ;
        const size_t hb1 = hb0 + FREQ;
        const float invN = 1.0f / 8192.0f;
#pragma unroll
        for (int q = 0; q < 16; ++q) {
            const int u = tid + q * THREADS;
            if (u == 0) {            // bin 0
                const int a = IDX(0);
                const float zr = re[a], zi = im[a];
                re[a] = zr * Hp[hb0].x * invN;
                im[a] = zi * Hp[hb1].x * invN;
            } else if (u == 1) {     // bin 4096 (Nyquist)
                const int a = IDX(1);
                const float zr = re[a], zi = im[a];
                re[a] = zr * Hp[hb0 + 4096].x * invN;
                im[a] = zi * Hp[hb1 + 4096].x * invN;
            } else {
                const int k  = ((u >> 9) & 15) | (((u >> 5) & 15) << 4)
                             | (((u >> 1) & 15) << 8) | ((u & 1) << 12);
                const int k2 = NFFT - k;
                const int p2 = ((k2 & 15) << 9) | (((k2 >> 4) & 15) << 5)
                             | (((k2 >> 8) & 15) << 1) | ((k2 >> 12) & 1);
                if (u < p2) {
                    const bool swapd = (k > NFFT / 2);
                    const int klo = swapd ? k2 : k;
                    const int pz = swapd ? p2 : u;
                    const int pw = swapd ? u : p2;
                    const int az = IDX(pz), aw = IDX(pw);
                    const float z1r = re[az], z1i = im[az];   // Z_klo
                    const float z2r = re[aw], z2i = im[aw];   // Z_{N-klo}
                    const float xar = 0.5f * (z1r + z2r), xai = 0.5f * (z1i - z2i);
                    const float xbr = 0.5f * (z1i + z2i), xbi = 0.5f * (z2r - z1r);
                    const float2 ha  = Hp[hb0 + klo];
                    const float2 hbv = Hp[hb1 + klo];
                    const float har = ha.x * invN,  hai = ha.y * invN;
                    const float hbr = hbv.x * invN, hbi = hbv.y * invN;
                    const float yar = xar * har - xai * hai;
                    const float yai = xar * hai + xai * har;
                    const float ybr = xbr * hbr - xbi * hbi;
                    const float ybi = xbr * hbi + xbi * hbr;
                    re[az] = yar - ybi;
                    im[az] = yai + ybr;
                    re[aw] = yar + ybi;
                    im[aw] = ybr - yai;
                }
            }
        }
    }
    __syncthreads();

    // ---- inverse P3': radix-2 undo via shfl, conj twiddle, inv DFT16 ----
    {
        const int b3 = tid >> 1, r3 = tid & 1;
        const int bb = b3 * 32 + r3;
        float sn, cs;
        __sincosf(TWO_PI * (float)r3 / 32.0f, &sn, &cs);
        const float2 wb = make_float2(cs, sn);
        float2 w = make_float2(1.0f, 0.0f);
#pragma unroll
        for (int u = 0; u < 16; ++u) {
            const int a = IDX(bb + u * 2);
            const float2 o = make_float2(re[a], im[a]);
            float2 p;
            p.x = __shfl_xor(o.x, 1);
            p.y = __shfl_xor(o.y, 1);
            const float2 U = r3 ? make_float2(p.x - o.x, p.y - o.y)
                                : make_float2(o.x + p.x, o.y + p.y);
            v[u] = (u == 0) ? U : cmul(U, w);
            w = cmul(w, wb);
        }
        dft16<1>(v);
#pragma unroll
        for (int t = 0; t < 16; ++t) {
            const int a = IDX(bb + t * 2);
            re[a] = v[R4[t]].x; im[a] = v[R4[t]].y;
        }
    }
    __syncthreads();

    // ---- inverse P2' ----
    {
        const int ub = tid >> 5, r2 = tid & 31;
        const int bb = ub * 512 + r2;
        float sn, cs;
        __sincosf(TWO_PI * (float)r2 / 512.0f, &sn, &cs);
        const float2 wb = make_float2(cs, sn);
        float2 w = make_float2(1.0f, 0.0f);
#pragma unroll
        for (int u = 0; u < 16; ++u) {
            const int a = IDX(bb + u * 32);
            const float2 U = make_float2(re[a], im[a]);
            v[u] = (u == 0) ? U : cmul(U, w);
            w = cmul(w, wb);
        }
        dft16<1>(v);
#pragma unroll
        for (int t = 0; t < 16; ++t) {
            const int a = IDX(bb + t * 32);
            re[a] = v[R4[t]].x; im[a] = v[R4[t]].y;
        }
    }
    __syncthreads();

    // ---- inverse P1': conj twiddle, inv DFT16, store to global ----
    {
        const int r1 = tid;
        float sn, cs;
        __sincosf(TWO_PI * (float)r1 / 8192.0f, &sn, &cs);
        const float2 wb = make_float2(cs, sn);
        float2 w = make_float2(1.0f, 0.0f);
#pragma unroll
        for (int u = 0; u < 16; ++u) {
            const int a = IDX(u * 512 + r1);
            const float2 U = make_float2(re[a], im[a]);
            v[u] = (u == 0) ? U : cmul(U, w);
            w = cmul(w, wb);
        }
        dft16<1>(v);
#pragma unroll
        for (int t = 0; t < 16; ++t)
            yp[base + (size_t)((t * 512 + r1) * FFD2)] = v[R4[t]];
    }
}

extern "C" void kernel_launch(void* const* d_in, const int* in_sizes, int n_in,
                              void* d_out, int out_size, void* d_ws, size_t ws_size,
                              hipStream_t stream) {
    const float* x = (const float*)d_in[0];
    const float* H = (const float*)d_in[1];
    float* y = (float*)d_out;
    fft_filter_kernel<<<dim3(2048), dim3(THREADS), 0, stream>>>(x, H, y);
}